// Round 2
// baseline (2380.009 us; speedup 1.0000x reference)
//
#include <hip/hip_runtime.h>
#include <hip/hip_bf16.h>

// GCN, 7 layers: h = relu(Â (h W) + b), Â = D^-1/2 (A + I) D^-1/2.
// Inputs (fp32/int32): x[100000,128], edge_index[2,1600000] (int32),
// edge_weight[1600000], then (W_l, b_l) for l=1..7.
// Output: fp32, [100000, 1]  (reference is all-fp32 JAX; harness follows ref dtype).

static constexpr int NN = 100000;
static constexpr int NE = 1600000;

// ---------------- graph normalization ----------------

__global__ void k_init_deg(float* __restrict__ deg) {
    int i = blockIdx.x * blockDim.x + threadIdx.x;
    if (i < NN) deg[i] = 1.0f;  // self-loop weight 1
}

__global__ void k_edge_deg(const int* __restrict__ col, const float* __restrict__ w,
                           float* __restrict__ deg) {
    int e = blockIdx.x * blockDim.x + threadIdx.x;
    if (e < NE) atomicAdd(&deg[col[e]], w[e]);
}

__global__ void k_dinv(float* __restrict__ deg) {
    int i = blockIdx.x * blockDim.x + threadIdx.x;
    if (i < NN) {
        float d = deg[i];
        deg[i] = (d > 0.0f) ? rsqrtf(d) : 0.0f;
    }
}

__global__ void k_norm(const int* __restrict__ row, const int* __restrict__ col,
                       const float* __restrict__ w, const float* __restrict__ dinv,
                       float* __restrict__ nrm) {
    int e = blockIdx.x * blockDim.x + threadIdx.x;
    if (e < NE) nrm[e] = dinv[row[e]] * w[e] * dinv[col[e]];
}

// ---------------- dense H = X * W ----------------
// block (64,4): threadIdx.x = output feature lane, threadIdx.y = node-in-block.
// X row is broadcast across f-lanes (one transaction), W reads coalesced across f.

template <int FIN, int FOUT>
__global__ void k_matmul(const float* __restrict__ X, const float* __restrict__ W,
                         float* __restrict__ H) {
    int f = threadIdx.x;
    int i = blockIdx.x * blockDim.y + threadIdx.y;
    if (i >= NN || f >= FOUT) return;
    const float* xr = X + (size_t)i * FIN;
    float acc = 0.0f;
#pragma unroll 8
    for (int k = 0; k < FIN; k += 2) {  // all FIN are even; rows stay 8B-aligned
        float2 xv = *(const float2*)(xr + k);
        acc = fmaf(xv.x, W[k * FOUT + f], acc);
        acc = fmaf(xv.y, W[(k + 1) * FOUT + f], acc);
    }
    H[(size_t)i * FOUT + f] = acc;
}

// ---------------- edge scatter (push, atomics) ----------------
// One thread per (edge, feature): F consecutive threads share one edge ->
// gather of F contiguous floats, atomics to F contiguous floats.

template <int F>
__global__ void k_scatter(const int* __restrict__ row, const int* __restrict__ col,
                          const float* __restrict__ nrm, const float* __restrict__ H,
                          float* __restrict__ A) {
    int idx = blockIdx.x * blockDim.x + threadIdx.x;
    if (idx >= NE * F) return;
    int e = idx / F;          // F is constexpr -> magic-multiply
    int f = idx - e * F;
    float v = H[(size_t)row[e] * F + f] * nrm[e];
    atomicAdd(&A[(size_t)col[e] * F + f], v);
}

// ---------------- epilogue: self-loop + bias (+ relu) ----------------

template <int F, bool RELU>
__global__ void k_epi(const float* __restrict__ A, const float* __restrict__ H,
                      const float* __restrict__ dinv, const float* __restrict__ b,
                      float* __restrict__ O) {
    int idx = blockIdx.x * blockDim.x + threadIdx.x;
    if (idx >= NN * F) return;
    int i = idx / F;
    int f = idx - i * F;
    float di = dinv[i];
    float v = fmaf(H[idx], di * di, A[idx]) + b[f];
    if (RELU) v = fmaxf(v, 0.0f);
    O[idx] = v;
}

__global__ void k_epi_final(const float* __restrict__ A, const float* __restrict__ H,
                            const float* __restrict__ dinv, const float* __restrict__ b,
                            float* __restrict__ O) {
    int i = blockIdx.x * blockDim.x + threadIdx.x;
    if (i >= NN) return;
    float di = dinv[i];
    float v = fmaf(H[i], di * di, A[i]) + b[0];
    O[i] = v;   // fp32 output, matching the reference dtype
}

// ---------------- launch ----------------

static inline size_t alignup(size_t x) { return (x + 255) & ~(size_t)255; }

extern "C" void kernel_launch(void* const* d_in, const int* in_sizes, int n_in,
                              void* d_out, int out_size, void* d_ws, size_t ws_size,
                              hipStream_t stream) {
    const float* x  = (const float*)d_in[0];
    const int*   ei = (const int*)d_in[1];
    const float* ew = (const float*)d_in[2];
    const float* Wp[7];
    const float* Bp[7];
    for (int l = 0; l < 7; ++l) {
        Wp[l] = (const float*)d_in[3 + 2 * l];
        Bp[l] = (const float*)d_in[4 + 2 * l];
    }
    const int* row = ei;       // source
    const int* col = ei + NE;  // destination

    // workspace carve: dinv | norm | H | AGG_a | AGG_b  (~67 MB)
    char* ws = (char*)d_ws;
    float* dinv = (float*)ws;                 ws += alignup((size_t)NN * 4);
    float* nrm  = (float*)ws;                 ws += alignup((size_t)NE * 4);
    float* Hb   = (float*)ws;                 ws += alignup((size_t)NN * 50 * 4);
    float* Aa   = (float*)ws;                 ws += alignup((size_t)NN * 50 * 4);
    float* Ab   = (float*)ws;                 ws += alignup((size_t)NN * 50 * 4);

    // normalization (shared by all layers)
    k_init_deg<<<(NN + 255) / 256, 256, 0, stream>>>(dinv);
    k_edge_deg<<<(NE + 255) / 256, 256, 0, stream>>>(col, ew, dinv);
    k_dinv<<<(NN + 255) / 256, 256, 0, stream>>>(dinv);
    k_norm<<<(NE + 255) / 256, 256, 0, stream>>>(row, col, ew, dinv, nrm);

    dim3 mmB(64, 4);
    int  mmG = (NN + 3) / 4;

#define LAYER(FIN, FOUT, RELU, XIN, AGG, LIDX)                                              \
    do {                                                                                    \
        k_matmul<FIN, FOUT><<<mmG, mmB, 0, stream>>>((XIN), Wp[LIDX], Hb);                  \
        hipMemsetAsync((AGG), 0, (size_t)NN * (FOUT) * 4, stream);                          \
        k_scatter<FOUT><<<(NE * (FOUT) + 255) / 256, 256, 0, stream>>>(row, col, nrm, Hb,   \
                                                                       (AGG));              \
        k_epi<FOUT, RELU><<<(NN * (FOUT) + 255) / 256, 256, 0, stream>>>((AGG), Hb, dinv,   \
                                                                         Bp[LIDX], (AGG));  \
    } while (0)

    LAYER(128, 50, true, x,  Aa, 0);
    LAYER(50,  50, true, Aa, Ab, 1);
    LAYER(50,  30, true, Ab, Aa, 2);
    LAYER(30,  30, true, Aa, Ab, 3);
    LAYER(30,  10, true, Ab, Aa, 4);
    LAYER(10,  10, true, Aa, Ab, 5);
#undef LAYER

    // layer 7: 10 -> 1, no relu, fp32 output
    k_matmul<10, 1><<<mmG, mmB, 0, stream>>>(Ab, Wp[6], Hb);
    hipMemsetAsync(Aa, 0, (size_t)NN * 4, stream);
    k_scatter<1><<<(NE + 255) / 256, 256, 0, stream>>>(row, col, nrm, Hb, Aa);
    k_epi_final<<<(NN + 255) / 256, 256, 0, stream>>>(Aa, Hb, dinv, Bp[6], (float*)d_out);
}

// Round 3
// 1324.133 us; speedup vs baseline: 1.7974x; 1.7974x over previous
//
#include <hip/hip_runtime.h>
#include <hip/hip_bf16.h>

// GCN, 7 layers: h = relu(Â (h W) + b), Â = D^-1/2 (A + I) D^-1/2.
// Round 3: atomic push-scatter -> CSR pull aggregation (counting sort by dst,
// built on-device every launch), with self-loop + bias + relu fused into the
// aggregation kernel. No per-layer atomics, no AGG memsets, no epilogues.

static constexpr int NN = 100000;
static constexpr int NE = 1600000;
static constexpr int NB = (NN + 255) / 256;  // 391 scan blocks

// ---------------- degree / normalization ----------------

__global__ void k_init_deg(float* __restrict__ deg) {
    int i = blockIdx.x * blockDim.x + threadIdx.x;
    if (i < NN) deg[i] = 1.0f;  // self-loop weight 1
}

__global__ void k_edge_deg(const int* __restrict__ col, const float* __restrict__ w,
                           float* __restrict__ deg) {
    int e = blockIdx.x * blockDim.x + threadIdx.x;
    if (e < NE) atomicAdd(&deg[col[e]], w[e]);
}

__global__ void k_dinv(float* __restrict__ deg) {
    int i = blockIdx.x * blockDim.x + threadIdx.x;
    if (i < NN) {
        float d = deg[i];
        deg[i] = (d > 0.0f) ? rsqrtf(d) : 0.0f;
    }
}

// ---------------- CSR build (counting sort by destination) ----------------

__global__ void k_hist(const int* __restrict__ col, int* __restrict__ cnt) {
    int e = blockIdx.x * blockDim.x + threadIdx.x;
    if (e < NE) atomicAdd(&cnt[col[e]], 1);
}

// per-block exclusive scan of cnt (in place) + block sums
__global__ void k_scan1(int* __restrict__ cnt, int* __restrict__ bsum) {
    __shared__ int lds[256];
    int i = blockIdx.x * 256 + threadIdx.x;
    int v = (i < NN) ? cnt[i] : 0;
    lds[threadIdx.x] = v;
    __syncthreads();
    for (int off = 1; off < 256; off <<= 1) {
        int t = (threadIdx.x >= off) ? lds[threadIdx.x - off] : 0;
        __syncthreads();
        lds[threadIdx.x] += t;
        __syncthreads();
    }
    if (i < NN) cnt[i] = lds[threadIdx.x] - v;  // exclusive within block
    if (threadIdx.x == 255) bsum[blockIdx.x] = lds[255];
}

// single-block exclusive scan of the 391 block sums
__global__ void k_scan2(int* __restrict__ bsum) {
    __shared__ int lds[512];
    int i = threadIdx.x;
    int v = (i < NB) ? bsum[i] : 0;
    lds[i] = v;
    __syncthreads();
    for (int off = 1; off < 512; off <<= 1) {
        int t = (i >= off) ? lds[i - off] : 0;
        __syncthreads();
        lds[i] += t;
        __syncthreads();
    }
    if (i < NB) bsum[i] = lds[i] - v;  // exclusive
}

// offs = cnt(excl-in-block) + bsum[block]; also seed cursor
__global__ void k_scan3(const int* __restrict__ cnt, const int* __restrict__ bsum,
                        int* __restrict__ offs, int* __restrict__ cursor) {
    int i = blockIdx.x * 256 + threadIdx.x;
    if (i < NN) {
        int o = cnt[i] + bsum[i >> 8];
        offs[i] = o;
        cursor[i] = o;
    }
    if (i == 0) offs[NN] = NE;
}

// scatter edges into CSR slots; fold the symmetric norm in here
__global__ void k_fill(const int* __restrict__ row, const int* __restrict__ col,
                       const float* __restrict__ ew, const float* __restrict__ dinv,
                       int* __restrict__ cursor, int* __restrict__ csrc,
                       float* __restrict__ cw) {
    int e = blockIdx.x * blockDim.x + threadIdx.x;
    if (e >= NE) return;
    int r = row[e], c = col[e];
    int p = atomicAdd(&cursor[c], 1);
    csrc[p] = r;
    cw[p] = dinv[r] * ew[e] * dinv[c];
}

// ---------------- dense H = X * W ----------------

template <int FIN, int FOUT>
__global__ void k_matmul(const float* __restrict__ X, const float* __restrict__ W,
                         float* __restrict__ H) {
    int f = threadIdx.x;
    int i = blockIdx.x * blockDim.y + threadIdx.y;
    if (i >= NN || f >= FOUT) return;
    const float* xr = X + (size_t)i * FIN;
    float acc = 0.0f;
#pragma unroll 8
    for (int k = 0; k < FIN; k += 2) {  // all FIN are even
        float2 xv = *(const float2*)(xr + k);
        acc = fmaf(xv.x, W[k * FOUT + f], acc);
        acc = fmaf(xv.y, W[(k + 1) * FOUT + f], acc);
    }
    H[(size_t)i * FOUT + f] = acc;
}

// ---------------- CSR pull aggregation + fused epilogue ----------------
// LPN lanes per destination node (LPN pow2 >= F); lane f handles feature f.
// Gather H[src*F+f] is coalesced across the group; one plain write per output.

template <int F, int LPN, bool RELU>
__global__ void k_agg(const int* __restrict__ offs, const int* __restrict__ csrc,
                      const float* __restrict__ cw, const float* __restrict__ H,
                      const float* __restrict__ dinv, const float* __restrict__ b,
                      float* __restrict__ O) {
    int t = blockIdx.x * blockDim.x + threadIdx.x;
    int g = t / LPN;                   // destination node
    int f = t - g * LPN;               // feature lane
    if (g >= NN || f >= F) return;
    int p = offs[g], pe = offs[g + 1];
    float acc = 0.0f;
    for (; p < pe; ++p) {
        int src = csrc[p];             // broadcast within group
        float w = cw[p];
        acc = fmaf(H[(size_t)src * F + f], w, acc);
    }
    float di = dinv[g];
    float v = acc + fmaf(H[(size_t)g * F + f], di * di, b[f]);  // self-loop + bias
    if (RELU) v = fmaxf(v, 0.0f);
    O[(size_t)g * F + f] = v;
}

// ---------------- launch ----------------

static inline size_t alignup(size_t x) { return (x + 255) & ~(size_t)255; }

extern "C" void kernel_launch(void* const* d_in, const int* in_sizes, int n_in,
                              void* d_out, int out_size, void* d_ws, size_t ws_size,
                              hipStream_t stream) {
    const float* x  = (const float*)d_in[0];
    const int*   ei = (const int*)d_in[1];
    const float* ew = (const float*)d_in[2];
    const float* Wp[7];
    const float* Bp[7];
    for (int l = 0; l < 7; ++l) {
        Wp[l] = (const float*)d_in[3 + 2 * l];
        Bp[l] = (const float*)d_in[4 + 2 * l];
    }
    const int* row = ei;       // source
    const int* col = ei + NE;  // destination

    // workspace carve (~82 MB)
    char* ws = (char*)d_ws;
    float* dinv  = (float*)ws;  ws += alignup((size_t)NN * 4);
    float* Hb    = (float*)ws;  ws += alignup((size_t)NN * 50 * 4);
    float* Aa    = (float*)ws;  ws += alignup((size_t)NN * 50 * 4);
    float* Ab    = (float*)ws;  ws += alignup((size_t)NN * 50 * 4);
    int*   cnt   = (int*)ws;    ws += alignup((size_t)NN * 4);
    int*   offs  = (int*)ws;    ws += alignup((size_t)(NN + 1) * 4);
    int*   cursor= (int*)ws;    ws += alignup((size_t)NN * 4);
    int*   bsum  = (int*)ws;    ws += alignup((size_t)NB * 4);
    int*   csrc  = (int*)ws;    ws += alignup((size_t)NE * 4);
    float* cw    = (float*)ws;  ws += alignup((size_t)NE * 4);

    // degree + inverse sqrt
    k_init_deg<<<(NN + 255) / 256, 256, 0, stream>>>(dinv);
    k_edge_deg<<<(NE + 255) / 256, 256, 0, stream>>>(col, ew, dinv);
    k_dinv<<<(NN + 255) / 256, 256, 0, stream>>>(dinv);

    // CSR build (counting sort by destination)
    hipMemsetAsync(cnt, 0, (size_t)NN * 4, stream);
    k_hist<<<(NE + 255) / 256, 256, 0, stream>>>(col, cnt);
    k_scan1<<<NB, 256, 0, stream>>>(cnt, bsum);
    k_scan2<<<1, 512, 0, stream>>>(bsum);
    k_scan3<<<NB, 256, 0, stream>>>(cnt, bsum, offs, cursor);
    k_fill<<<(NE + 255) / 256, 256, 0, stream>>>(row, col, ew, dinv, cursor, csrc, cw);

#define LAYER(FIN, FOUT, LPN, RELU, XIN, OUT, LIDX, BX, BY)                                 \
    do {                                                                                    \
        k_matmul<FIN, FOUT><<<(NN + (BY)-1) / (BY), dim3(BX, BY), 0, stream>>>(             \
            (XIN), Wp[LIDX], Hb);                                                           \
        k_agg<FOUT, LPN, RELU><<<((size_t)NN * (LPN) + 255) / 256, 256, 0, stream>>>(       \
            offs, csrc, cw, Hb, dinv, Bp[LIDX], (OUT));                                     \
    } while (0)

    LAYER(128, 50, 64, true, x,  Aa, 0, 64, 4);
    LAYER(50,  50, 64, true, Aa, Ab, 1, 64, 4);
    LAYER(50,  30, 32, true, Ab, Aa, 2, 32, 8);
    LAYER(30,  30, 32, true, Aa, Ab, 3, 32, 8);
    LAYER(30,  10, 16, true, Ab, Aa, 4, 16, 16);
    LAYER(10,  10, 16, true, Aa, Ab, 5, 16, 16);
    LAYER(10,  1,  1, false, Ab, (float*)d_out, 6, 16, 16);
#undef LAYER
}

// Round 4
// 941.443 us; speedup vs baseline: 2.5280x; 1.4065x over previous
//
#include <hip/hip_runtime.h>

// GCN, 7 layers: h = relu(Â (h W) + b), Â = D^-1/2 (A + I) D^-1/2.
// Round 4: matmul rewritten (LDS-staged W, 8 nodes/wave, vectorized X,
// multi-chain accumulation); agg inner loop uses packed int2 (src,w) +
// 4-way unroll for memory-level parallelism.

static constexpr int NN = 100000;
static constexpr int NE = 1600000;
static constexpr int NB = (NN + 255) / 256;  // 391 scan blocks

// ---------------- degree / normalization ----------------

__global__ void k_init_deg(float* __restrict__ deg) {
    int i = blockIdx.x * blockDim.x + threadIdx.x;
    if (i < NN) deg[i] = 1.0f;  // self-loop weight 1
}

__global__ void k_edge_deg(const int* __restrict__ col, const float* __restrict__ w,
                           float* __restrict__ deg) {
    int e = blockIdx.x * blockDim.x + threadIdx.x;
    if (e < NE) atomicAdd(&deg[col[e]], w[e]);
}

__global__ void k_dinv(float* __restrict__ deg) {
    int i = blockIdx.x * blockDim.x + threadIdx.x;
    if (i < NN) {
        float d = deg[i];
        deg[i] = (d > 0.0f) ? rsqrtf(d) : 0.0f;
    }
}

// ---------------- CSR build (counting sort by destination) ----------------

__global__ void k_hist(const int* __restrict__ col, int* __restrict__ cnt) {
    int e = blockIdx.x * blockDim.x + threadIdx.x;
    if (e < NE) atomicAdd(&cnt[col[e]], 1);
}

__global__ void k_scan1(int* __restrict__ cnt, int* __restrict__ bsum) {
    __shared__ int lds[256];
    int i = blockIdx.x * 256 + threadIdx.x;
    int v = (i < NN) ? cnt[i] : 0;
    lds[threadIdx.x] = v;
    __syncthreads();
    for (int off = 1; off < 256; off <<= 1) {
        int t = (threadIdx.x >= off) ? lds[threadIdx.x - off] : 0;
        __syncthreads();
        lds[threadIdx.x] += t;
        __syncthreads();
    }
    if (i < NN) cnt[i] = lds[threadIdx.x] - v;  // exclusive within block
    if (threadIdx.x == 255) bsum[blockIdx.x] = lds[255];
}

__global__ void k_scan2(int* __restrict__ bsum) {
    __shared__ int lds[512];
    int i = threadIdx.x;
    int v = (i < NB) ? bsum[i] : 0;
    lds[i] = v;
    __syncthreads();
    for (int off = 1; off < 512; off <<= 1) {
        int t = (i >= off) ? lds[i - off] : 0;
        __syncthreads();
        lds[i] += t;
        __syncthreads();
    }
    if (i < NB) bsum[i] = lds[i] - v;  // exclusive
}

__global__ void k_scan3(const int* __restrict__ cnt, const int* __restrict__ bsum,
                        int* __restrict__ offs, int* __restrict__ cursor) {
    int i = blockIdx.x * 256 + threadIdx.x;
    if (i < NN) {
        int o = cnt[i] + bsum[i >> 8];
        offs[i] = o;
        cursor[i] = o;
    }
    if (i == 0) offs[NN] = NE;
}

// scatter edges into CSR slots; pack (src, norm-weight) into one int2
__global__ void k_fill(const int* __restrict__ row, const int* __restrict__ col,
                       const float* __restrict__ ew, const float* __restrict__ dinv,
                       int* __restrict__ cursor, int2* __restrict__ csw) {
    int e = blockIdx.x * blockDim.x + threadIdx.x;
    if (e >= NE) return;
    int r = row[e], c = col[e];
    int p = atomicAdd(&cursor[c], 1);
    csw[p] = make_int2(r, __float_as_int(dinv[r] * ew[e] * dinv[c]));
}

// ---------------- dense H = X * W ----------------
// Block = 256 threads = 4 waves. W staged in LDS. Each wave: NPT nodes,
// lane = output feature. X loads are wave-broadcast float4/float2; 8
// independent accumulator chains give ~4:1 FMA:VMEM and deep MLP.

template <int FIN, int FOUT, int NPT>
__global__ __launch_bounds__(256) void k_matmul(const float* __restrict__ X,
                                                const float* __restrict__ W,
                                                float* __restrict__ H) {
    __shared__ float sW[FIN * FOUT];
    for (int t = threadIdx.x; t < FIN * FOUT; t += 256) sW[t] = W[t];
    __syncthreads();

    const int f = threadIdx.x & 63;
    const int node0 = (blockIdx.x * 4 + (threadIdx.x >> 6)) * NPT;
    if (node0 >= NN || f >= FOUT) return;  // after barrier: safe

    float acc[NPT];
#pragma unroll
    for (int j = 0; j < NPT; ++j) acc[j] = 0.0f;

    constexpr int KV = (FIN % 4 == 0) ? 4 : 2;
    for (int k = 0; k < FIN; k += KV) {
        float xv[NPT][KV];
        if constexpr (KV == 4) {
#pragma unroll
            for (int j = 0; j < NPT; ++j)
                *(float4*)xv[j] = *(const float4*)(X + (size_t)(node0 + j) * FIN + k);
        } else {
#pragma unroll
            for (int j = 0; j < NPT; ++j)
                *(float2*)xv[j] = *(const float2*)(X + (size_t)(node0 + j) * FIN + k);
        }
#pragma unroll
        for (int kk = 0; kk < KV; ++kk) {
            float wv = sW[(k + kk) * FOUT + f];
#pragma unroll
            for (int j = 0; j < NPT; ++j) acc[j] = fmaf(xv[j][kk], wv, acc[j]);
        }
    }
#pragma unroll
    for (int j = 0; j < NPT; ++j) H[(size_t)(node0 + j) * FOUT + f] = acc[j];
}

// FOUT=1 special case: one thread per node (generic kernel would use 1/64 lanes).
template <int FIN>
__global__ void k_matmul_1(const float* __restrict__ X, const float* __restrict__ W,
                           float* __restrict__ H) {
    int i = blockIdx.x * blockDim.x + threadIdx.x;
    if (i >= NN) return;
    const float* xr = X + (size_t)i * FIN;
    float acc = 0.0f;
#pragma unroll
    for (int k = 0; k < FIN; k += 2) {  // FIN even; W index uniform -> s_load
        float2 xv = *(const float2*)(xr + k);
        acc = fmaf(xv.x, W[k], acc);
        acc = fmaf(xv.y, W[k + 1], acc);
    }
    H[i] = acc;
}

// ---------------- CSR pull aggregation + fused epilogue ----------------
// LPN lanes (pow2 >= F) per destination node. int2-packed (src,w) halves the
// inner-loop VMEM count; 4-way unroll = 4 independent gather chains in flight.

template <int F, int LPN, bool RELU>
__global__ __launch_bounds__(256) void k_agg(const int* __restrict__ offs,
                                             const int2* __restrict__ csw,
                                             const float* __restrict__ H,
                                             const float* __restrict__ dinv,
                                             const float* __restrict__ b,
                                             float* __restrict__ O) {
    int t = blockIdx.x * blockDim.x + threadIdx.x;
    int g = t / LPN;
    int f = t - g * LPN;
    if (g >= NN || f >= F) return;
    int p = offs[g];
    const int pe = offs[g + 1];
    float a0 = 0.0f, a1 = 0.0f, a2 = 0.0f, a3 = 0.0f;
    for (; p + 4 <= pe; p += 4) {
        int2 e0 = csw[p], e1 = csw[p + 1], e2 = csw[p + 2], e3 = csw[p + 3];
        float h0 = H[(size_t)e0.x * F + f];
        float h1 = H[(size_t)e1.x * F + f];
        float h2 = H[(size_t)e2.x * F + f];
        float h3 = H[(size_t)e3.x * F + f];
        a0 = fmaf(h0, __int_as_float(e0.y), a0);
        a1 = fmaf(h1, __int_as_float(e1.y), a1);
        a2 = fmaf(h2, __int_as_float(e2.y), a2);
        a3 = fmaf(h3, __int_as_float(e3.y), a3);
    }
    for (; p < pe; ++p) {
        int2 e0 = csw[p];
        a0 = fmaf(H[(size_t)e0.x * F + f], __int_as_float(e0.y), a0);
    }
    float di = dinv[g];
    float v = ((a0 + a1) + (a2 + a3)) + fmaf(H[(size_t)g * F + f], di * di, b[f]);
    if (RELU) v = fmaxf(v, 0.0f);
    O[(size_t)g * F + f] = v;
}

// ---------------- launch ----------------

static inline size_t alignup(size_t x) { return (x + 255) & ~(size_t)255; }

extern "C" void kernel_launch(void* const* d_in, const int* in_sizes, int n_in,
                              void* d_out, int out_size, void* d_ws, size_t ws_size,
                              hipStream_t stream) {
    const float* x  = (const float*)d_in[0];
    const int*   ei = (const int*)d_in[1];
    const float* ew = (const float*)d_in[2];
    const float* Wp[7];
    const float* Bp[7];
    for (int l = 0; l < 7; ++l) {
        Wp[l] = (const float*)d_in[3 + 2 * l];
        Bp[l] = (const float*)d_in[4 + 2 * l];
    }
    const int* row = ei;       // source
    const int* col = ei + NE;  // destination

    // workspace carve (~82 MB)
    char* ws = (char*)d_ws;
    float* dinv  = (float*)ws;  ws += alignup((size_t)NN * 4);
    float* Hb    = (float*)ws;  ws += alignup((size_t)NN * 50 * 4);
    float* Aa    = (float*)ws;  ws += alignup((size_t)NN * 50 * 4);
    float* Ab    = (float*)ws;  ws += alignup((size_t)NN * 50 * 4);
    int*   cnt   = (int*)ws;    ws += alignup((size_t)NN * 4);
    int*   offs  = (int*)ws;    ws += alignup((size_t)(NN + 1) * 4);
    int*   cursor= (int*)ws;    ws += alignup((size_t)NN * 4);
    int*   bsum  = (int*)ws;    ws += alignup((size_t)NB * 4);
    int2*  csw   = (int2*)ws;   ws += alignup((size_t)NE * 8);

    // degree + inverse sqrt
    k_init_deg<<<(NN + 255) / 256, 256, 0, stream>>>(dinv);
    k_edge_deg<<<(NE + 255) / 256, 256, 0, stream>>>(col, ew, dinv);
    k_dinv<<<(NN + 255) / 256, 256, 0, stream>>>(dinv);

    // CSR build (counting sort by destination)
    hipMemsetAsync(cnt, 0, (size_t)NN * 4, stream);
    k_hist<<<(NE + 255) / 256, 256, 0, stream>>>(col, cnt);
    k_scan1<<<NB, 256, 0, stream>>>(cnt, bsum);
    k_scan2<<<1, 512, 0, stream>>>(bsum);
    k_scan3<<<NB, 256, 0, stream>>>(cnt, bsum, offs, cursor);
    k_fill<<<(NE + 255) / 256, 256, 0, stream>>>(row, col, ew, dinv, cursor, csw);

    constexpr int NPT = 8;
    const int mmG = NN / (4 * NPT);  // 3125, exact

#define LAYER(FIN, FOUT, LPN, RELU, XIN, OUT, LIDX)                                         \
    do {                                                                                    \
        k_matmul<FIN, FOUT, NPT><<<mmG, 256, 0, stream>>>((XIN), Wp[LIDX], Hb);             \
        k_agg<FOUT, LPN, RELU><<<((size_t)NN * (LPN) + 255) / 256, 256, 0, stream>>>(       \
            offs, csw, Hb, dinv, Bp[LIDX], (OUT));                                          \
    } while (0)

    LAYER(128, 50, 64, true, x,  Aa, 0);
    LAYER(50,  50, 64, true, Aa, Ab, 1);
    LAYER(50,  30, 32, true, Ab, Aa, 2);
    LAYER(30,  30, 32, true, Aa, Ab, 3);
    LAYER(30,  10, 16, true, Ab, Aa, 4);
    LAYER(10,  10, 16, true, Aa, Ab, 5);
#undef LAYER

    // layer 7: 10 -> 1, no relu
    k_matmul_1<10><<<(NN + 255) / 256, 256, 0, stream>>>(Ab, Wp[6], Hb);
    k_agg<1, 1, false><<<(NN + 255) / 256, 256, 0, stream>>>(offs, csw, Hb, dinv, Bp[6],
                                                             (float*)d_out);
}

// Round 5
// 760.322 us; speedup vs baseline: 3.1303x; 1.2382x over previous
//
#include <hip/hip_runtime.h>

// GCN, 7 layers: h = relu(Â (h W) + b), Â = D^-1/2 (A + I) D^-1/2.
// Round 5: matmul -> thread-per-node with register accumulators + scalar
// (s_load) W reads; agg -> float2 feature lanes, aligned int4 edge loads,
// 4 accumulator chains.

static constexpr int NN = 100000;
static constexpr int NE = 1600000;
static constexpr int NB = (NN + 255) / 256;  // 391 scan blocks

// ---------------- degree / normalization ----------------

__global__ void k_init_deg(float* __restrict__ deg) {
    int i = blockIdx.x * blockDim.x + threadIdx.x;
    if (i < NN) deg[i] = 1.0f;  // self-loop weight 1
}

__global__ void k_edge_deg(const int* __restrict__ col, const float* __restrict__ w,
                           float* __restrict__ deg) {
    int e = blockIdx.x * blockDim.x + threadIdx.x;
    if (e < NE) atomicAdd(&deg[col[e]], w[e]);
}

__global__ void k_dinv(float* __restrict__ deg) {
    int i = blockIdx.x * blockDim.x + threadIdx.x;
    if (i < NN) {
        float d = deg[i];
        deg[i] = (d > 0.0f) ? rsqrtf(d) : 0.0f;
    }
}

// ---------------- CSR build (counting sort by destination) ----------------

__global__ void k_hist(const int* __restrict__ col, int* __restrict__ cnt) {
    int e = blockIdx.x * blockDim.x + threadIdx.x;
    if (e < NE) atomicAdd(&cnt[col[e]], 1);
}

__global__ void k_scan1(int* __restrict__ cnt, int* __restrict__ bsum) {
    __shared__ int lds[256];
    int i = blockIdx.x * 256 + threadIdx.x;
    int v = (i < NN) ? cnt[i] : 0;
    lds[threadIdx.x] = v;
    __syncthreads();
    for (int off = 1; off < 256; off <<= 1) {
        int t = (threadIdx.x >= off) ? lds[threadIdx.x - off] : 0;
        __syncthreads();
        lds[threadIdx.x] += t;
        __syncthreads();
    }
    if (i < NN) cnt[i] = lds[threadIdx.x] - v;  // exclusive within block
    if (threadIdx.x == 255) bsum[blockIdx.x] = lds[255];
}

__global__ void k_scan2(int* __restrict__ bsum) {
    __shared__ int lds[512];
    int i = threadIdx.x;
    int v = (i < NB) ? bsum[i] : 0;
    lds[i] = v;
    __syncthreads();
    for (int off = 1; off < 512; off <<= 1) {
        int t = (i >= off) ? lds[i - off] : 0;
        __syncthreads();
        lds[i] += t;
        __syncthreads();
    }
    if (i < NB) bsum[i] = lds[i] - v;  // exclusive
}

__global__ void k_scan3(const int* __restrict__ cnt, const int* __restrict__ bsum,
                        int* __restrict__ offs, int* __restrict__ cursor) {
    int i = blockIdx.x * 256 + threadIdx.x;
    if (i < NN) {
        int o = cnt[i] + bsum[i >> 8];
        offs[i] = o;
        cursor[i] = o;
    }
    if (i == 0) offs[NN] = NE;
}

// scatter edges into CSR slots; pack (src, norm-weight) into one int2
__global__ void k_fill(const int* __restrict__ row, const int* __restrict__ col,
                       const float* __restrict__ ew, const float* __restrict__ dinv,
                       int* __restrict__ cursor, int2* __restrict__ csw) {
    int e = blockIdx.x * blockDim.x + threadIdx.x;
    if (e >= NE) return;
    int r = row[e], c = col[e];
    int p = atomicAdd(&cursor[c], 1);
    csw[p] = make_int2(r, __float_as_int(dinv[r] * ew[e] * dinv[c]));
}

// ---------------- dense H = X * W ----------------
// Thread per node. acc[FOUT] in VGPRs. X: per-lane float4/float2 loads.
// W: indexed only by loop-uniform expressions -> compiler emits s_load
// (scalar pipe), leaving ~1 VMEM per 100-200 FMAs.

template <int FIN, int FOUT>
__global__ __launch_bounds__(256) void k_matmul(const float* __restrict__ X,
                                                const float* __restrict__ W,
                                                float* __restrict__ H) {
    int i = blockIdx.x * 256 + threadIdx.x;
    if (i >= NN) return;
    const float* xr = X + (size_t)i * FIN;
    float acc[FOUT];
#pragma unroll
    for (int j = 0; j < FOUT; ++j) acc[j] = 0.0f;

    constexpr int KV = (FIN % 4 == 0) ? 4 : 2;
    for (int k = 0; k < FIN; k += KV) {
        float xv[KV];
        if constexpr (KV == 4) *(float4*)xv = *(const float4*)(xr + k);
        else                   *(float2*)xv = *(const float2*)(xr + k);
#pragma unroll
        for (int kk = 0; kk < KV; ++kk)
#pragma unroll
            for (int j = 0; j < FOUT; ++j)
                acc[j] = fmaf(xv[kk], W[(k + kk) * FOUT + j], acc[j]);
    }
    float* hr = H + (size_t)i * FOUT;
#pragma unroll
    for (int j = 0; j < FOUT; ++j) hr[j] = acc[j];
}

// FOUT=1 special case.
template <int FIN>
__global__ void k_matmul_1(const float* __restrict__ X, const float* __restrict__ W,
                           float* __restrict__ H) {
    int i = blockIdx.x * blockDim.x + threadIdx.x;
    if (i >= NN) return;
    const float* xr = X + (size_t)i * FIN;
    float acc = 0.0f;
#pragma unroll
    for (int k = 0; k < FIN; k += 2) {
        float2 xv = *(const float2*)(xr + k);
        acc = fmaf(xv.x, W[k], acc);
        acc = fmaf(xv.y, W[k + 1], acc);
    }
    H[i] = acc;
}

// ---------------- CSR pull aggregation + fused epilogue ----------------
// LPN lanes per destination node; each lane handles a float2 of features
// (FH = F/2 active lanes). Edge records read as 16B-aligned int4 pairs;
// 4 independent accumulator chains.

template <int F, int LPN, bool RELU>
__global__ __launch_bounds__(256) void k_agg2(const int* __restrict__ offs,
                                              const int2* __restrict__ csw,
                                              const float* __restrict__ H,
                                              const float* __restrict__ dinv,
                                              const float* __restrict__ b,
                                              float* __restrict__ O) {
    constexpr int FH = F / 2;
    int t = blockIdx.x * blockDim.x + threadIdx.x;
    int g = t / LPN;
    int f = t - g * LPN;           // float2 lane
    if (g >= NN || f >= FH) return;
    int p = offs[g];
    const int pe = offs[g + 1];

    float2 a0 = {0.f, 0.f}, a1 = {0.f, 0.f}, a2 = {0.f, 0.f}, a3 = {0.f, 0.f};

    if (p < pe && (p & 1)) {       // peel to even p for 16B-aligned int4 loads
        int2 e = csw[p];
        float2 h = *(const float2*)(H + (size_t)e.x * F + 2 * f);
        float w = __int_as_float(e.y);
        a0.x = fmaf(h.x, w, a0.x); a0.y = fmaf(h.y, w, a0.y);
        ++p;
    }
    for (; p + 4 <= pe; p += 4) {
        int4 e01 = *(const int4*)(csw + p);       // {src0,w0,src1,w1}
        int4 e23 = *(const int4*)(csw + p + 2);   // {src2,w2,src3,w3}
        float2 h0 = *(const float2*)(H + (size_t)e01.x * F + 2 * f);
        float2 h1 = *(const float2*)(H + (size_t)e01.z * F + 2 * f);
        float2 h2 = *(const float2*)(H + (size_t)e23.x * F + 2 * f);
        float2 h3 = *(const float2*)(H + (size_t)e23.z * F + 2 * f);
        float w0 = __int_as_float(e01.y), w1 = __int_as_float(e01.w);
        float w2 = __int_as_float(e23.y), w3 = __int_as_float(e23.w);
        a0.x = fmaf(h0.x, w0, a0.x); a0.y = fmaf(h0.y, w0, a0.y);
        a1.x = fmaf(h1.x, w1, a1.x); a1.y = fmaf(h1.y, w1, a1.y);
        a2.x = fmaf(h2.x, w2, a2.x); a2.y = fmaf(h2.y, w2, a2.y);
        a3.x = fmaf(h3.x, w3, a3.x); a3.y = fmaf(h3.y, w3, a3.y);
    }
    for (; p < pe; ++p) {
        int2 e = csw[p];
        float2 h = *(const float2*)(H + (size_t)e.x * F + 2 * f);
        float w = __int_as_float(e.y);
        a0.x = fmaf(h.x, w, a0.x); a0.y = fmaf(h.y, w, a0.y);
    }

    float di = dinv[g];
    float d2 = di * di;
    float2 hs = *(const float2*)(H + (size_t)g * F + 2 * f);
    float2 bb = *(const float2*)(b + 2 * f);
    float vx = ((a0.x + a1.x) + (a2.x + a3.x)) + fmaf(hs.x, d2, bb.x);
    float vy = ((a0.y + a1.y) + (a2.y + a3.y)) + fmaf(hs.y, d2, bb.y);
    if (RELU) { vx = fmaxf(vx, 0.0f); vy = fmaxf(vy, 0.0f); }
    *(float2*)(O + (size_t)g * F + 2 * f) = make_float2(vx, vy);
}

// F=1 aggregation (final layer): one thread per node.
__global__ void k_agg1(const int* __restrict__ offs, const int2* __restrict__ csw,
                       const float* __restrict__ H, const float* __restrict__ dinv,
                       const float* __restrict__ b, float* __restrict__ O) {
    int g = blockIdx.x * blockDim.x + threadIdx.x;
    if (g >= NN) return;
    int p = offs[g];
    const int pe = offs[g + 1];
    float a0 = 0.f, a1 = 0.f, a2 = 0.f, a3 = 0.f;
    for (; p + 4 <= pe; p += 4) {
        int2 e0 = csw[p], e1 = csw[p + 1], e2 = csw[p + 2], e3 = csw[p + 3];
        a0 = fmaf(H[e0.x], __int_as_float(e0.y), a0);
        a1 = fmaf(H[e1.x], __int_as_float(e1.y), a1);
        a2 = fmaf(H[e2.x], __int_as_float(e2.y), a2);
        a3 = fmaf(H[e3.x], __int_as_float(e3.y), a3);
    }
    for (; p < pe; ++p) {
        int2 e0 = csw[p];
        a0 = fmaf(H[e0.x], __int_as_float(e0.y), a0);
    }
    float di = dinv[g];
    O[g] = ((a0 + a1) + (a2 + a3)) + fmaf(H[g], di * di, b[0]);
}

// ---------------- launch ----------------

static inline size_t alignup(size_t x) { return (x + 255) & ~(size_t)255; }

extern "C" void kernel_launch(void* const* d_in, const int* in_sizes, int n_in,
                              void* d_out, int out_size, void* d_ws, size_t ws_size,
                              hipStream_t stream) {
    const float* x  = (const float*)d_in[0];
    const int*   ei = (const int*)d_in[1];
    const float* ew = (const float*)d_in[2];
    const float* Wp[7];
    const float* Bp[7];
    for (int l = 0; l < 7; ++l) {
        Wp[l] = (const float*)d_in[3 + 2 * l];
        Bp[l] = (const float*)d_in[4 + 2 * l];
    }
    const int* row = ei;       // source
    const int* col = ei + NE;  // destination

    // workspace carve (~82 MB)
    char* ws = (char*)d_ws;
    float* dinv  = (float*)ws;  ws += alignup((size_t)NN * 4);
    float* Hb    = (float*)ws;  ws += alignup((size_t)NN * 50 * 4);
    float* Aa    = (float*)ws;  ws += alignup((size_t)NN * 50 * 4);
    float* Ab    = (float*)ws;  ws += alignup((size_t)NN * 50 * 4);
    int*   cnt   = (int*)ws;    ws += alignup((size_t)NN * 4);
    int*   offs  = (int*)ws;    ws += alignup((size_t)(NN + 1) * 4);
    int*   cursor= (int*)ws;    ws += alignup((size_t)NN * 4);
    int*   bsum  = (int*)ws;    ws += alignup((size_t)NB * 4);
    int2*  csw   = (int2*)ws;   ws += alignup((size_t)NE * 8);

    // degree + inverse sqrt
    k_init_deg<<<(NN + 255) / 256, 256, 0, stream>>>(dinv);
    k_edge_deg<<<(NE + 255) / 256, 256, 0, stream>>>(col, ew, dinv);
    k_dinv<<<(NN + 255) / 256, 256, 0, stream>>>(dinv);

    // CSR build (counting sort by destination)
    hipMemsetAsync(cnt, 0, (size_t)NN * 4, stream);
    k_hist<<<(NE + 255) / 256, 256, 0, stream>>>(col, cnt);
    k_scan1<<<NB, 256, 0, stream>>>(cnt, bsum);
    k_scan2<<<1, 512, 0, stream>>>(bsum);
    k_scan3<<<NB, 256, 0, stream>>>(cnt, bsum, offs, cursor);
    k_fill<<<(NE + 255) / 256, 256, 0, stream>>>(row, col, ew, dinv, cursor, csw);

    const int mmG = (NN + 255) / 256;

#define LAYER(FIN, FOUT, LPN, RELU, XIN, OUT, LIDX)                                         \
    do {                                                                                    \
        k_matmul<FIN, FOUT><<<mmG, 256, 0, stream>>>((XIN), Wp[LIDX], Hb);                  \
        k_agg2<FOUT, LPN, RELU><<<((size_t)NN * (LPN) + 255) / 256, 256, 0, stream>>>(      \
            offs, csw, Hb, dinv, Bp[LIDX], (OUT));                                          \
    } while (0)

    LAYER(128, 50, 32, true, x,  Aa, 0);
    LAYER(50,  50, 32, true, Aa, Ab, 1);
    LAYER(50,  30, 16, true, Ab, Aa, 2);
    LAYER(30,  30, 16, true, Aa, Ab, 3);
    LAYER(30,  10, 8,  true, Ab, Aa, 4);
    LAYER(10,  10, 8,  true, Aa, Ab, 5);
#undef LAYER

    // layer 7: 10 -> 1, no relu
    k_matmul_1<10><<<mmG, 256, 0, stream>>>(Ab, Wp[6], Hb);
    k_agg1<<<mmG, 256, 0, stream>>>(offs, csw, Hb, dinv, Bp[6], (float*)d_out);
}